// Round 4
// baseline (333.522 us; speedup 1.0000x reference)
//
#include <hip/hip_runtime.h>
#include <math.h>

#define BATCH 256
#define PRE   64     // k
#define NEXT  32     // K
#define DIN   128    // d
#define DOUT  64     // D

typedef __attribute__((ext_vector_type(8))) short bf16x8;
typedef __attribute__((ext_vector_type(4))) float f32x4;

__device__ __forceinline__ unsigned short f2bf(float f) {
    unsigned u = __float_as_uint(f);
    unsigned r = (u + 0x7fffu + ((u >> 16) & 1u)) >> 16;   // RNE
    return (unsigned short)r;
}
__device__ __forceinline__ float bf2f(unsigned short h) {
    return __uint_as_float(((unsigned)h) << 16);
}

#define WFRAG_S 10   // dwords per fragment slot (8 data + 2 pad)

// ---------------- MFMA GEMM -> p fp32 + s0 = sum_k p (pass-0 fusion) ---------
// Body is the EXACT verified R2 kernel (~73us; the R3 K-pair restructure
// regressed it to 109us -- reverted). New: epilogue also atomicAdds each
// result into s0[b,K,D] (2 MB, L2-resident, 64 kk-writers per address).
// s0 lets route skip its uniform-weight pass 0 entirely (1/3 of its traffic).
__global__ __launch_bounds__(256, 2) void gemm_kernel(const float* __restrict__ x,
                                                      const float* __restrict__ W,
                                                      float* __restrict__ p,
                                                      float* __restrict__ s0,
                                                      int b0)
{
    __shared__ float xs[128 * 40];              // 20.5 KB x-tile [row][d]
    __shared__ unsigned wpk[256 * WFRAG_S];     // 10 KB packed W frags
    const int K    = blockIdx.x;
    const int kk   = blockIdx.y;
    const int bt   = blockIdx.z;
    const int t    = threadIdx.x;
    const int wave = t >> 6;
    const int lane = t & 63;
    const int ln   = lane & 15;
    const int quad = lane >> 4;
    const int row0 = bt * 128 + wave * 32;      // local (chunk) row base

    f32x4 acc[2][4];
#pragma unroll
    for (int mt = 0; mt < 2; ++mt)
#pragma unroll
        for (int nt = 0; nt < 4; ++nt) acc[mt][nt] = (f32x4){0.f, 0.f, 0.f, 0.f};

    const float* Wk = W + (size_t)(kk * NEXT + K) * DIN * DOUT;

    for (int dc = 0; dc < 4; ++dc) {
        __syncthreads();
        // stage x tile: 128 rows x 32 d (coalesced float4)
#pragma unroll
        for (int i = 0; i < 4; ++i) {
            const int f   = t + 256 * i;    // 0..1023 float4s
            const int row = f >> 3;
            const int d4  = f & 7;
            float4 v = *(const float4*)(x + ((size_t)(b0 + bt * 128 + row) * PRE + kk) * DIN + dc * 32 + d4 * 4);
            *(float4*)&xs[row * 40 + d4 * 4] = v;
        }
        // stage W slab 32x64, convert to packed bf16 hi/lo in fragment order
#pragma unroll
        for (int it = 0; it < 8; ++it) {
            const int e  = it * 256 + t;    // 0..2047
            const int dl = e >> 6;          // 0..31
            const int D  = e & 63;
            float v = Wk[(size_t)(dc * 32 + dl) * DOUT + D];
            unsigned short h = f2bf(v);
            unsigned short l = f2bf(v - bf2f(h));
            const int fr = ((D >> 4) * 64 + (dl >> 3) * 16 + (D & 15));
            wpk[fr * WFRAG_S + (dl & 7)] = (unsigned)h | ((unsigned)l << 16);
        }
        __syncthreads();

        // A fragments from xs + hi/lo split
        bf16x8 ah[2], al[2];
#pragma unroll
        for (int mt = 0; mt < 2; ++mt) {
            const float* xa = &xs[(wave * 32 + mt * 16 + ln) * 40 + quad * 8];
            float4 v0 = *(const float4*)xa;
            float4 v1 = *(const float4*)(xa + 4);
            float xv[8] = {v0.x, v0.y, v0.z, v0.w, v1.x, v1.y, v1.z, v1.w};
#pragma unroll
            for (int j = 0; j < 8; ++j) {
                unsigned short h = f2bf(xv[j]);
                ah[mt][j] = (short)h;
                al[mt][j] = (short)f2bf(xv[j] - bf2f(h));
            }
        }
        // B fragments from packed LDS (b64 reads, 8B-aligned at stride 40B)
        bf16x8 bh[4], bl[4];
#pragma unroll
        for (int nt = 0; nt < 4; ++nt) {
            const unsigned* wp = &wpk[(nt * 64 + quad * 16 + ln) * WFRAG_S];
            unsigned pk[8];
#pragma unroll
            for (int i2 = 0; i2 < 4; ++i2) *(uint2*)&pk[i2 * 2] = *(const uint2*)&wp[i2 * 2];
            union { bf16x8 v; unsigned u[4]; } BH, BL;
#pragma unroll
            for (int i2 = 0; i2 < 4; ++i2) {
                BH.u[i2] = (pk[2 * i2] & 0xffffu) | (pk[2 * i2 + 1] << 16);
                BL.u[i2] = (pk[2 * i2] >> 16) | (pk[2 * i2 + 1] & 0xffff0000u);
            }
            bh[nt] = BH.v; bl[nt] = BL.v;
        }
#pragma unroll
        for (int mt = 0; mt < 2; ++mt)
#pragma unroll
            for (int nt = 0; nt < 4; ++nt) {
                acc[mt][nt] = __builtin_amdgcn_mfma_f32_16x16x32_bf16(ah[mt], bh[nt], acc[mt][nt], 0, 0, 0);
                acc[mt][nt] = __builtin_amdgcn_mfma_f32_16x16x32_bf16(al[mt], bh[nt], acc[mt][nt], 0, 0, 0);
                acc[mt][nt] = __builtin_amdgcn_mfma_f32_16x16x32_bf16(ah[mt], bl[nt], acc[mt][nt], 0, 0, 0);
            }
    }

    // store natural fp32 + accumulate s0[b,K,D] = sum_kk p (device atomics)
#pragma unroll
    for (int mt = 0; mt < 2; ++mt)
#pragma unroll
        for (int nt = 0; nt < 4; ++nt) {
            const int D = nt * 16 + ln;
#pragma unroll
            for (int r = 0; r < 4; ++r) {
                const int row = row0 + mt * 16 + quad * 4 + r;
                const float v = acc[mt][nt][r];
                p[((size_t)(row * PRE + kk) * NEXT + K) * DOUT + D] = v;
                atomicAdd(&s0[(size_t)(b0 + row) * 2048 + K * 64 + D], v);
            }
        }
}

// ---------------- Routing: 2 fused passes over fp32 p -------------------------
// Pass 0 (uniform weights) is precomputed by gemm as s0; qsum is initialized
// to q1 = squash(s0/32) and the kernel runs the 2 remaining passes:
//   pass 0 here: logits = p.q1        -> q2, qsum += q2
//   pass 1 here: logits = p.(q1+q2)   -> q3 -> out
// Structure otherwise identical to the verified R2 route (105us, occupancy
// 40%): 16 waves, 8-deep float4 double-buffered prefetch, two-stage wave
// reduction, qsum stride 68 floats (b128 at 2 lanes/bank).
#define QSTR 68
#define QBUF (32 * QSTR)   // 2176 floats

__global__ __launch_bounds__(1024, 1) void route_kernel(const float* __restrict__ p,
                                                        float* __restrict__ out,
                                                        int b0)
{
    __shared__ float qpart[8 * QBUF];   // 68 KB shared partial-q buffers
    __shared__ float qsum[QBUF];        // 8.5 KB running Q
    const int b    = blockIdx.x;
    const int t    = threadIdx.x;
    const int w    = t >> 6;      // 0..15
    const int lane = t & 63;
    const int g    = lane >> 4;   // 0..3
    const int m    = lane & 15;   // 0..15
    const float4* pb = (const float4*)(p + (size_t)b * (PRE * NEXT * DOUT));

    // qsum = q1 = squash(s0 / 32); thread t owns (K=t>>5, pair=t&31).
    // Threads of one K group are lanes [0..31] or [32..63] of a wave, so
    // shfl_xor 1..16 reduces within the group.
    {
        const int Kq = t >> 5, pr = t & 31;
        const float* s0p = out + (size_t)(b0 + b) * 2048 + Kq * 64 + pr * 2;
        float vx = s0p[0] * (1.0f / 32.0f);
        float vy = s0p[1] * (1.0f / 32.0f);
        float s2 = vx * vx + vy * vy;
        s2 += __shfl_xor(s2, 1);
        s2 += __shfl_xor(s2, 2);
        s2 += __shfl_xor(s2, 4);
        s2 += __shfl_xor(s2, 8);
        s2 += __shfl_xor(s2, 16);
        float fsc = s2 / ((1.f + s2) * sqrtf(s2 + 1e-8f));
        float* qd = &qsum[Kq * QSTR + pr * 2];
        qd[0] = vx * fsc; qd[1] = vy * fsc;
    }
    __syncthreads();

    for (int pass = 0; pass < 2; ++pass) {
        float4 qa[8];
#pragma unroll
        for (int j = 0; j < 8; ++j) qa[j] = (float4){0.f, 0.f, 0.f, 0.f};

        float4 pv[2][8];
        {
            const size_t sb = (size_t)w * 512;
#pragma unroll
            for (int j = 0; j < 8; ++j) pv[0][j] = pb[sb + j * 64 + lane];
        }
#pragma unroll
        for (int i = 0; i < 4; ++i) {
            const int buf = i & 1;
            if (i < 3) {
                const size_t sb = (size_t)((i + 1) * 16 + w) * 512;
#pragma unroll
                for (int j = 0; j < 8; ++j) pv[buf ^ 1][j] = pb[sb + j * 64 + lane];
            }
            float c[8];
            // logits = p . Q, Q streamed from LDS (b128, 16B-aligned)
#pragma unroll
            for (int j = 0; j < 8; ++j) {
                float4 qv = *(const float4*)&qsum[(j * 4 + g) * QSTR + m * 4];
                float d = pv[buf][j].x * qv.x + pv[buf][j].y * qv.y
                        + pv[buf][j].z * qv.z + pv[buf][j].w * qv.w;
                d += __shfl_xor(d, 1);
                d += __shfl_xor(d, 2);
                d += __shfl_xor(d, 4);
                d += __shfl_xor(d, 8);
                c[j] = d;
            }
            float mx = c[0];
#pragma unroll
            for (int j = 1; j < 8; ++j) mx = fmaxf(mx, c[j]);
            mx = fmaxf(mx, __shfl_xor(mx, 16));
            mx = fmaxf(mx, __shfl_xor(mx, 32));
            float s = 0.f;
#pragma unroll
            for (int j = 0; j < 8; ++j) { c[j] = __expf(c[j] - mx); s += c[j]; }
            s += __shfl_xor(s, 16);
            s += __shfl_xor(s, 32);
            float inv = 1.0f / s;
#pragma unroll
            for (int j = 0; j < 8; ++j) c[j] *= inv;
#pragma unroll
            for (int j = 0; j < 8; ++j) {
                qa[j].x += c[j] * pv[buf][j].x;
                qa[j].y += c[j] * pv[buf][j].y;
                qa[j].z += c[j] * pv[buf][j].z;
                qa[j].w += c[j] * pv[buf][j].w;
            }
        }
        // stage A: waves 0-7 write their partials
        if (w < 8) {
#pragma unroll
            for (int j = 0; j < 8; ++j)
                *(float4*)&qpart[w * QBUF + (j * 4 + g) * QSTR + m * 4] = qa[j];
        }
        __syncthreads();
        // stage B: waves 8-15 accumulate into buffer w-8 (disjoint slots)
        if (w >= 8) {
#pragma unroll
            for (int j = 0; j < 8; ++j) {
                float* qd = &qpart[(w - 8) * QBUF + (j * 4 + g) * QSTR + m * 4];
                float4 old = *(const float4*)qd;
                old.x += qa[j].x; old.y += qa[j].y; old.z += qa[j].z; old.w += qa[j].w;
                *(float4*)qd = old;
            }
        }
        __syncthreads();

        // tree-sum over 8 buffers + squash; thread t owns (K=t>>5, pair=t&31)
        {
            const int Kq = t >> 5, pr = t & 31;
            float vx = 0.f, vy = 0.f;
#pragma unroll
            for (int ww = 0; ww < 8; ++ww) {
                const float* s2p = &qpart[ww * QBUF + Kq * QSTR + pr * 2];
                vx += s2p[0]; vy += s2p[1];
            }
            float s2 = vx * vx + vy * vy;
            s2 += __shfl_xor(s2, 1);
            s2 += __shfl_xor(s2, 2);
            s2 += __shfl_xor(s2, 4);
            s2 += __shfl_xor(s2, 8);
            s2 += __shfl_xor(s2, 16);
            float fsc = s2 / ((1.f + s2) * sqrtf(s2 + 1e-8f));
            vx *= fsc; vy *= fsc;
            if (pass == 0) {
                float* qd = &qsum[Kq * QSTR + pr * 2];
                qd[0] += vx; qd[1] += vy;
            } else {
                float* od = out + (size_t)(b0 + b) * 2048 + Kq * 64 + pr * 2;
                od[0] = vx; od[1] = vy;
            }
        }
        if (pass == 0) __syncthreads();   // qsum visible + qpart reads done
    }
}

extern "C" void kernel_launch(void* const* d_in, const int* in_sizes, int n_in,
                              void* d_out, int out_size, void* d_ws, size_t ws_size,
                              hipStream_t stream) {
    const float* x = (const float*)d_in[0];
    const float* W = (const float*)d_in[1];
    float* out = (float*)d_out;
    float* p   = (float*)d_ws;    // p owns the whole workspace

    // full batch in one shot if ws >= 128 MiB (proven); else 2 chunks
    const int chunk = (ws_size >= (size_t)134217728) ? 256 : 128;

    for (int b0 = 0; b0 < BATCH; b0 += chunk) {
        // s0 accumulates in the out buffer (same [b, K*64+D] layout) --
        // zero it for this chunk before gemm's atomics.
        hipMemsetAsync((char*)out + (size_t)b0 * 2048 * 4, 0,
                       (size_t)chunk * 2048 * 4, stream);
        gemm_kernel<<<dim3(NEXT, PRE, chunk / 128), 256, 0, stream>>>(x, W, p, out, b0);
        route_kernel<<<chunk, 1024, 0, stream>>>(p, out, b0);
    }
}

// Round 5
// 253.150 us; speedup vs baseline: 1.3175x; 1.3175x over previous
//
#include <hip/hip_runtime.h>
#include <math.h>

#define BATCH 256
#define PRE   64     // k
#define NEXT  32     // K
#define DIN   128    // d
#define DOUT  64     // D

typedef __attribute__((ext_vector_type(8))) short bf16x8;
typedef __attribute__((ext_vector_type(4))) float f32x4;

__device__ __forceinline__ unsigned short f2bf(float f) {
    unsigned u = __float_as_uint(f);
    unsigned r = (u + 0x7fffu + ((u >> 16) & 1u)) >> 16;   // RNE
    return (unsigned short)r;
}
__device__ __forceinline__ float bf2f(unsigned short h) {
    return __uint_as_float(((unsigned)h) << 16);
}

#define WFRAG_S 10   // dwords per fragment slot (8 data + 2 pad)

// ---------------- MFMA GEMM -> p fp32, NATURAL [lb,k,K,D] layout --------------
// EXACT verified R2 body (~73us). R3 K-pair restructure (109us) and R4 s0
// atomics (~131us) both regressed -- reverted.
__global__ __launch_bounds__(256, 2) void gemm_kernel(const float* __restrict__ x,
                                                      const float* __restrict__ W,
                                                      float* __restrict__ p,
                                                      int b0)
{
    __shared__ float xs[128 * 40];              // 20.5 KB x-tile [row][d]
    __shared__ unsigned wpk[256 * WFRAG_S];     // 10 KB packed W frags
    const int K    = blockIdx.x;
    const int kk   = blockIdx.y;
    const int bt   = blockIdx.z;
    const int t    = threadIdx.x;
    const int wave = t >> 6;
    const int lane = t & 63;
    const int ln   = lane & 15;
    const int quad = lane >> 4;
    const int row0 = bt * 128 + wave * 32;      // local (chunk) row base

    f32x4 acc[2][4];
#pragma unroll
    for (int mt = 0; mt < 2; ++mt)
#pragma unroll
        for (int nt = 0; nt < 4; ++nt) acc[mt][nt] = (f32x4){0.f, 0.f, 0.f, 0.f};

    const float* Wk = W + (size_t)(kk * NEXT + K) * DIN * DOUT;

    for (int dc = 0; dc < 4; ++dc) {
        __syncthreads();
        // stage x tile: 128 rows x 32 d (coalesced float4)
#pragma unroll
        for (int i = 0; i < 4; ++i) {
            const int f   = t + 256 * i;    // 0..1023 float4s
            const int row = f >> 3;
            const int d4  = f & 7;
            float4 v = *(const float4*)(x + ((size_t)(b0 + bt * 128 + row) * PRE + kk) * DIN + dc * 32 + d4 * 4);
            *(float4*)&xs[row * 40 + d4 * 4] = v;
        }
        // stage W slab 32x64, convert to packed bf16 hi/lo in fragment order
#pragma unroll
        for (int it = 0; it < 8; ++it) {
            const int e  = it * 256 + t;    // 0..2047
            const int dl = e >> 6;          // 0..31
            const int D  = e & 63;
            float v = Wk[(size_t)(dc * 32 + dl) * DOUT + D];
            unsigned short h = f2bf(v);
            unsigned short l = f2bf(v - bf2f(h));
            const int fr = ((D >> 4) * 64 + (dl >> 3) * 16 + (D & 15));
            wpk[fr * WFRAG_S + (dl & 7)] = (unsigned)h | ((unsigned)l << 16);
        }
        __syncthreads();

        // A fragments from xs + hi/lo split
        bf16x8 ah[2], al[2];
#pragma unroll
        for (int mt = 0; mt < 2; ++mt) {
            const float* xa = &xs[(wave * 32 + mt * 16 + ln) * 40 + quad * 8];
            float4 v0 = *(const float4*)xa;
            float4 v1 = *(const float4*)(xa + 4);
            float xv[8] = {v0.x, v0.y, v0.z, v0.w, v1.x, v1.y, v1.z, v1.w};
#pragma unroll
            for (int j = 0; j < 8; ++j) {
                unsigned short h = f2bf(xv[j]);
                ah[mt][j] = (short)h;
                al[mt][j] = (short)f2bf(xv[j] - bf2f(h));
            }
        }
        // B fragments from packed LDS (b64 reads, 8B-aligned at stride 40B)
        bf16x8 bh[4], bl[4];
#pragma unroll
        for (int nt = 0; nt < 4; ++nt) {
            const unsigned* wp = &wpk[(nt * 64 + quad * 16 + ln) * WFRAG_S];
            unsigned pk[8];
#pragma unroll
            for (int i2 = 0; i2 < 4; ++i2) *(uint2*)&pk[i2 * 2] = *(const uint2*)&wp[i2 * 2];
            union { bf16x8 v; unsigned u[4]; } BH, BL;
#pragma unroll
            for (int i2 = 0; i2 < 4; ++i2) {
                BH.u[i2] = (pk[2 * i2] & 0xffffu) | (pk[2 * i2 + 1] << 16);
                BL.u[i2] = (pk[2 * i2] >> 16) | (pk[2 * i2 + 1] & 0xffff0000u);
            }
            bh[nt] = BH.v; bl[nt] = BL.v;
        }
#pragma unroll
        for (int mt = 0; mt < 2; ++mt)
#pragma unroll
            for (int nt = 0; nt < 4; ++nt) {
                acc[mt][nt] = __builtin_amdgcn_mfma_f32_16x16x32_bf16(ah[mt], bh[nt], acc[mt][nt], 0, 0, 0);
                acc[mt][nt] = __builtin_amdgcn_mfma_f32_16x16x32_bf16(al[mt], bh[nt], acc[mt][nt], 0, 0, 0);
                acc[mt][nt] = __builtin_amdgcn_mfma_f32_16x16x32_bf16(ah[mt], bl[nt], acc[mt][nt], 0, 0, 0);
            }
    }

    // store natural fp32: C/D map col=ln, row=quad*4+r; 16 ln-lanes = 64B lines
#pragma unroll
    for (int mt = 0; mt < 2; ++mt)
#pragma unroll
        for (int nt = 0; nt < 4; ++nt) {
            const int D = nt * 16 + ln;
#pragma unroll
            for (int r = 0; r < 4; ++r) {
                const int row = row0 + mt * 16 + quad * 4 + r;
                p[((size_t)(row * PRE + kk) * NEXT + K) * DOUT + D] = acc[mt][nt][r];
            }
        }
}

// ---------------- Routing: 3 fused passes over fp32 p -------------------------
// R2 structure (verified 105us) with ONE change: LDS padded past 80 KB.
// At 78336 B two blocks/CU fit, so the compiler's scheduler targets 8
// waves/SIMD = 64 VGPR and SINKS the pv[2][8] prefetch into its uses
// (VGPR_Count=64 proves the double buffer was collapsed -- live set of the
// source is ~110 regs). Grid = 1 block/CU, so that occupancy never existed.
// LDS 83136 B -> only 1 block/CU fits -> 4 waves/SIMD target -> 128-VGPR
// budget -> prefetch loads stay issued 8-deep ahead of compute.
#define QSTR 68
#define QBUF (32 * QSTR)   // 2176 floats
#define QSUM_PAD 1200      // pushes LDS to 83136 B > 80 KB (occupancy fence)

__global__ __launch_bounds__(1024, 1) void route_kernel(const float* __restrict__ p,
                                                        float* __restrict__ out,
                                                        int b0)
{
    __shared__ float qpart[8 * QBUF];        // 68 KB shared partial-q buffers
    __shared__ float qsum[QBUF + QSUM_PAD];  // 8.5 KB running Q + fence pad
    const int b    = blockIdx.x;
    const int t    = threadIdx.x;
    const int w    = t >> 6;      // 0..15
    const int lane = t & 63;
    const int g    = lane >> 4;   // 0..3
    const int m    = lane & 15;   // 0..15
    const float4* pb = (const float4*)(p + (size_t)b * (PRE * NEXT * DOUT));

    for (int idx = t; idx < QBUF; idx += 1024) qsum[idx] = 0.f;
    __syncthreads();

    for (int pass = 0; pass < 3; ++pass) {
        float4 qa[8];
#pragma unroll
        for (int j = 0; j < 8; ++j) qa[j] = (float4){0.f, 0.f, 0.f, 0.f};

        float4 pv[2][8];
        {
            const size_t sb = (size_t)w * 512;
#pragma unroll
            for (int j = 0; j < 8; ++j) pv[0][j] = pb[sb + j * 64 + lane];
        }
#pragma unroll
        for (int i = 0; i < 4; ++i) {
            const int buf = i & 1;
            if (i < 3) {
                const size_t sb = (size_t)((i + 1) * 16 + w) * 512;
#pragma unroll
                for (int j = 0; j < 8; ++j) pv[buf ^ 1][j] = pb[sb + j * 64 + lane];
            }
            float c[8];
            if (pass == 0) {
#pragma unroll
                for (int j = 0; j < 8; ++j) c[j] = 1.0f / 32.0f;
            } else {
                // logits = p . Q, Q streamed from LDS (b128, 16B-aligned)
#pragma unroll
                for (int j = 0; j < 8; ++j) {
                    float4 qv = *(const float4*)&qsum[(j * 4 + g) * QSTR + m * 4];
                    float d = pv[buf][j].x * qv.x + pv[buf][j].y * qv.y
                            + pv[buf][j].z * qv.z + pv[buf][j].w * qv.w;
                    d += __shfl_xor(d, 1);
                    d += __shfl_xor(d, 2);
                    d += __shfl_xor(d, 4);
                    d += __shfl_xor(d, 8);
                    c[j] = d;
                }
                float mx = c[0];
#pragma unroll
                for (int j = 1; j < 8; ++j) mx = fmaxf(mx, c[j]);
                mx = fmaxf(mx, __shfl_xor(mx, 16));
                mx = fmaxf(mx, __shfl_xor(mx, 32));
                float s = 0.f;
#pragma unroll
                for (int j = 0; j < 8; ++j) { c[j] = __expf(c[j] - mx); s += c[j]; }
                s += __shfl_xor(s, 16);
                s += __shfl_xor(s, 32);
                float inv = 1.0f / s;
#pragma unroll
                for (int j = 0; j < 8; ++j) c[j] *= inv;
            }
#pragma unroll
            for (int j = 0; j < 8; ++j) {
                qa[j].x += c[j] * pv[buf][j].x;
                qa[j].y += c[j] * pv[buf][j].y;
                qa[j].z += c[j] * pv[buf][j].z;
                qa[j].w += c[j] * pv[buf][j].w;
            }
        }
        // stage A: waves 0-7 write their partials
        if (w < 8) {
#pragma unroll
            for (int j = 0; j < 8; ++j)
                *(float4*)&qpart[w * QBUF + (j * 4 + g) * QSTR + m * 4] = qa[j];
        }
        __syncthreads();
        // stage B: waves 8-15 accumulate into buffer w-8 (disjoint slots)
        if (w >= 8) {
#pragma unroll
            for (int j = 0; j < 8; ++j) {
                float* qd = &qpart[(w - 8) * QBUF + (j * 4 + g) * QSTR + m * 4];
                float4 old = *(const float4*)qd;
                old.x += qa[j].x; old.y += qa[j].y; old.z += qa[j].z; old.w += qa[j].w;
                *(float4*)qd = old;
            }
        }
        __syncthreads();

        // tree-sum over 8 buffers + squash; thread t owns (K=t>>5, pair=t&31)
        {
            const int Kq = t >> 5, pr = t & 31;
            float vx = 0.f, vy = 0.f;
#pragma unroll
            for (int ww = 0; ww < 8; ++ww) {
                const float* s2p = &qpart[ww * QBUF + Kq * QSTR + pr * 2];
                vx += s2p[0]; vy += s2p[1];
            }
            float s2 = vx * vx + vy * vy;
            s2 += __shfl_xor(s2, 1);
            s2 += __shfl_xor(s2, 2);
            s2 += __shfl_xor(s2, 4);
            s2 += __shfl_xor(s2, 8);
            s2 += __shfl_xor(s2, 16);
            float fsc = s2 / ((1.f + s2) * sqrtf(s2 + 1e-8f));
            vx *= fsc; vy *= fsc;
            if (pass < 2) {
                float* qd = &qsum[Kq * QSTR + pr * 2];
                qd[0] += vx; qd[1] += vy;
            } else {
                float* od = out + (size_t)(b0 + b) * 2048 + Kq * 64 + pr * 2;
                od[0] = vx; od[1] = vy;
            }
        }
        if (pass < 2) __syncthreads();   // qsum visible + qpart reads done
    }
}

extern "C" void kernel_launch(void* const* d_in, const int* in_sizes, int n_in,
                              void* d_out, int out_size, void* d_ws, size_t ws_size,
                              hipStream_t stream) {
    const float* x = (const float*)d_in[0];
    const float* W = (const float*)d_in[1];
    float* out = (float*)d_out;
    float* p   = (float*)d_ws;    // p owns the whole workspace

    // full batch in one shot if ws >= 128 MiB (proven); else 2 chunks
    const int chunk = (ws_size >= (size_t)134217728) ? 256 : 128;

    for (int b0 = 0; b0 < BATCH; b0 += chunk) {
        gemm_kernel<<<dim3(NEXT, PRE, chunk / 128), 256, 0, stream>>>(x, W, p, b0);
        route_kernel<<<chunk, 1024, 0, stream>>>(p, out, b0);
    }
}

// Round 6
// 250.732 us; speedup vs baseline: 1.3302x; 1.0096x over previous
//
#include <hip/hip_runtime.h>
#include <math.h>

#define BATCH 256
#define PRE   64     // k
#define NEXT  32     // K
#define DIN   128    // d
#define DOUT  64     // D

typedef __attribute__((ext_vector_type(8))) short bf16x8;
typedef __attribute__((ext_vector_type(4))) float f32x4;

__device__ __forceinline__ unsigned short f2bf(float f) {
    unsigned u = __float_as_uint(f);
    unsigned r = (u + 0x7fffu + ((u >> 16) & 1u)) >> 16;   // RNE
    return (unsigned short)r;
}
__device__ __forceinline__ float bf2f(unsigned short h) {
    return __uint_as_float(((unsigned)h) << 16);
}

#define WFRAG_S 10   // dwords per fragment slot (8 data + 2 pad)

// ---------------- MFMA GEMM -> p fp32, NATURAL [lb,k,K,D] layout --------------
// EXACT verified R2 body (~75us). R3 K-pair restructure (109us) and R4 s0
// atomics (~131us) both regressed -- reverted and kept frozen.
__global__ __launch_bounds__(256, 2) void gemm_kernel(const float* __restrict__ x,
                                                      const float* __restrict__ W,
                                                      float* __restrict__ p,
                                                      int b0)
{
    __shared__ float xs[128 * 40];              // 20.5 KB x-tile [row][d]
    __shared__ unsigned wpk[256 * WFRAG_S];     // 10 KB packed W frags
    const int K    = blockIdx.x;
    const int kk   = blockIdx.y;
    const int bt   = blockIdx.z;
    const int t    = threadIdx.x;
    const int wave = t >> 6;
    const int lane = t & 63;
    const int ln   = lane & 15;
    const int quad = lane >> 4;
    const int row0 = bt * 128 + wave * 32;      // local (chunk) row base

    f32x4 acc[2][4];
#pragma unroll
    for (int mt = 0; mt < 2; ++mt)
#pragma unroll
        for (int nt = 0; nt < 4; ++nt) acc[mt][nt] = (f32x4){0.f, 0.f, 0.f, 0.f};

    const float* Wk = W + (size_t)(kk * NEXT + K) * DIN * DOUT;

    for (int dc = 0; dc < 4; ++dc) {
        __syncthreads();
        // stage x tile: 128 rows x 32 d (coalesced float4)
#pragma unroll
        for (int i = 0; i < 4; ++i) {
            const int f   = t + 256 * i;    // 0..1023 float4s
            const int row = f >> 3;
            const int d4  = f & 7;
            float4 v = *(const float4*)(x + ((size_t)(b0 + bt * 128 + row) * PRE + kk) * DIN + dc * 32 + d4 * 4);
            *(float4*)&xs[row * 40 + d4 * 4] = v;
        }
        // stage W slab 32x64, convert to packed bf16 hi/lo in fragment order
#pragma unroll
        for (int it = 0; it < 8; ++it) {
            const int e  = it * 256 + t;    // 0..2047
            const int dl = e >> 6;          // 0..31
            const int D  = e & 63;
            float v = Wk[(size_t)(dc * 32 + dl) * DOUT + D];
            unsigned short h = f2bf(v);
            unsigned short l = f2bf(v - bf2f(h));
            const int fr = ((D >> 4) * 64 + (dl >> 3) * 16 + (D & 15));
            wpk[fr * WFRAG_S + (dl & 7)] = (unsigned)h | ((unsigned)l << 16);
        }
        __syncthreads();

        // A fragments from xs + hi/lo split
        bf16x8 ah[2], al[2];
#pragma unroll
        for (int mt = 0; mt < 2; ++mt) {
            const float* xa = &xs[(wave * 32 + mt * 16 + ln) * 40 + quad * 8];
            float4 v0 = *(const float4*)xa;
            float4 v1 = *(const float4*)(xa + 4);
            float xv[8] = {v0.x, v0.y, v0.z, v0.w, v1.x, v1.y, v1.z, v1.w};
#pragma unroll
            for (int j = 0; j < 8; ++j) {
                unsigned short h = f2bf(xv[j]);
                ah[mt][j] = (short)h;
                al[mt][j] = (short)f2bf(xv[j] - bf2f(h));
            }
        }
        // B fragments from packed LDS (b64 reads, 8B-aligned at stride 40B)
        bf16x8 bh[4], bl[4];
#pragma unroll
        for (int nt = 0; nt < 4; ++nt) {
            const unsigned* wp = &wpk[(nt * 64 + quad * 16 + ln) * WFRAG_S];
            unsigned pk[8];
#pragma unroll
            for (int i2 = 0; i2 < 4; ++i2) *(uint2*)&pk[i2 * 2] = *(const uint2*)&wp[i2 * 2];
            union { bf16x8 v; unsigned u[4]; } BH, BL;
#pragma unroll
            for (int i2 = 0; i2 < 4; ++i2) {
                BH.u[i2] = (pk[2 * i2] & 0xffffu) | (pk[2 * i2 + 1] << 16);
                BL.u[i2] = (pk[2 * i2] >> 16) | (pk[2 * i2 + 1] & 0xffff0000u);
            }
            bh[nt] = BH.v; bl[nt] = BL.v;
        }
#pragma unroll
        for (int mt = 0; mt < 2; ++mt)
#pragma unroll
            for (int nt = 0; nt < 4; ++nt) {
                acc[mt][nt] = __builtin_amdgcn_mfma_f32_16x16x32_bf16(ah[mt], bh[nt], acc[mt][nt], 0, 0, 0);
                acc[mt][nt] = __builtin_amdgcn_mfma_f32_16x16x32_bf16(al[mt], bh[nt], acc[mt][nt], 0, 0, 0);
                acc[mt][nt] = __builtin_amdgcn_mfma_f32_16x16x32_bf16(ah[mt], bl[nt], acc[mt][nt], 0, 0, 0);
            }
    }

    // store natural fp32: C/D map col=ln, row=quad*4+r; 16 ln-lanes = 64B lines
#pragma unroll
    for (int mt = 0; mt < 2; ++mt)
#pragma unroll
        for (int nt = 0; nt < 4; ++nt) {
            const int D = nt * 16 + ln;
#pragma unroll
            for (int r = 0; r < 4; ++r) {
                const int row = row0 + mt * 16 + quad * 4 + r;
                p[((size_t)(row * PRE + kk) * NEXT + K) * DOUT + D] = acc[mt][nt][r];
            }
        }
}

// ---------------- Routing: 3 fused passes over fp32 p -------------------------
// R2 structure. R5 showed the compiler's VGPR target is LDS-blind: it still
// allocated 64 VGPRs (8-waves/EU occupancy target) even though LDS caps us at
// 1 block/CU = 4 waves/EU, so the pv[2][8] double-buffer was collapsed and
// loads sunk to uses (latency-serialized: hbm 39%, VALUBusy 10%).
// Fix: PIN the occupancy with amdgpu_waves_per_eu(4,4) -> 128-VGPR budget ->
// the ~115-reg live set with the 8-deep prefetch held fits, scheduler hoists
// the next-iteration loads and emits fine-grained vmcnt waits.
#define QSTR 68
#define QBUF (32 * QSTR)   // 2176 floats
#define QSUM_PAD 1200      // LDS > 80 KB (harmless; kept from R5)

__global__ __launch_bounds__(1024)
__attribute__((amdgpu_waves_per_eu(4, 4)))
void route_kernel(const float* __restrict__ p,
                  float* __restrict__ out,
                  int b0)
{
    __shared__ float qpart[8 * QBUF];        // 68 KB shared partial-q buffers
    __shared__ float qsum[QBUF + QSUM_PAD];  // 8.5 KB running Q + fence pad
    const int b    = blockIdx.x;
    const int t    = threadIdx.x;
    const int w    = t >> 6;      // 0..15
    const int lane = t & 63;
    const int g    = lane >> 4;   // 0..3
    const int m    = lane & 15;   // 0..15
    const float4* pb = (const float4*)(p + (size_t)b * (PRE * NEXT * DOUT));

    for (int idx = t; idx < QBUF; idx += 1024) qsum[idx] = 0.f;
    __syncthreads();

    for (int pass = 0; pass < 3; ++pass) {
        float4 qa[8];
#pragma unroll
        for (int j = 0; j < 8; ++j) qa[j] = (float4){0.f, 0.f, 0.f, 0.f};

        float4 pv[2][8];
        {
            const size_t sb = (size_t)w * 512;
#pragma unroll
            for (int j = 0; j < 8; ++j) pv[0][j] = pb[sb + j * 64 + lane];
        }
#pragma unroll
        for (int i = 0; i < 4; ++i) {
            const int buf = i & 1;
            if (i < 3) {
                const size_t sb = (size_t)((i + 1) * 16 + w) * 512;
#pragma unroll
                for (int j = 0; j < 8; ++j) pv[buf ^ 1][j] = pb[sb + j * 64 + lane];
            }
            float c[8];
            if (pass == 0) {
#pragma unroll
                for (int j = 0; j < 8; ++j) c[j] = 1.0f / 32.0f;
            } else {
                // logits = p . Q, Q streamed from LDS (b128, 16B-aligned)
#pragma unroll
                for (int j = 0; j < 8; ++j) {
                    float4 qv = *(const float4*)&qsum[(j * 4 + g) * QSTR + m * 4];
                    float d = pv[buf][j].x * qv.x + pv[buf][j].y * qv.y
                            + pv[buf][j].z * qv.z + pv[buf][j].w * qv.w;
                    d += __shfl_xor(d, 1);
                    d += __shfl_xor(d, 2);
                    d += __shfl_xor(d, 4);
                    d += __shfl_xor(d, 8);
                    c[j] = d;
                }
                float mx = c[0];
#pragma unroll
                for (int j = 1; j < 8; ++j) mx = fmaxf(mx, c[j]);
                mx = fmaxf(mx, __shfl_xor(mx, 16));
                mx = fmaxf(mx, __shfl_xor(mx, 32));
                float s = 0.f;
#pragma unroll
                for (int j = 0; j < 8; ++j) { c[j] = __expf(c[j] - mx); s += c[j]; }
                s += __shfl_xor(s, 16);
                s += __shfl_xor(s, 32);
                float inv = 1.0f / s;
#pragma unroll
                for (int j = 0; j < 8; ++j) c[j] *= inv;
            }
#pragma unroll
            for (int j = 0; j < 8; ++j) {
                qa[j].x += c[j] * pv[buf][j].x;
                qa[j].y += c[j] * pv[buf][j].y;
                qa[j].z += c[j] * pv[buf][j].z;
                qa[j].w += c[j] * pv[buf][j].w;
            }
        }
        // stage A: waves 0-7 write their partials
        if (w < 8) {
#pragma unroll
            for (int j = 0; j < 8; ++j)
                *(float4*)&qpart[w * QBUF + (j * 4 + g) * QSTR + m * 4] = qa[j];
        }
        __syncthreads();
        // stage B: waves 8-15 accumulate into buffer w-8 (disjoint slots)
        if (w >= 8) {
#pragma unroll
            for (int j = 0; j < 8; ++j) {
                float* qd = &qpart[(w - 8) * QBUF + (j * 4 + g) * QSTR + m * 4];
                float4 old = *(const float4*)qd;
                old.x += qa[j].x; old.y += qa[j].y; old.z += qa[j].z; old.w += qa[j].w;
                *(float4*)qd = old;
            }
        }
        __syncthreads();

        // tree-sum over 8 buffers + squash; thread t owns (K=t>>5, pair=t&31)
        {
            const int Kq = t >> 5, pr = t & 31;
            float vx = 0.f, vy = 0.f;
#pragma unroll
            for (int ww = 0; ww < 8; ++ww) {
                const float* s2p = &qpart[ww * QBUF + Kq * QSTR + pr * 2];
                vx += s2p[0]; vy += s2p[1];
            }
            float s2 = vx * vx + vy * vy;
            s2 += __shfl_xor(s2, 1);
            s2 += __shfl_xor(s2, 2);
            s2 += __shfl_xor(s2, 4);
            s2 += __shfl_xor(s2, 8);
            s2 += __shfl_xor(s2, 16);
            float fsc = s2 / ((1.f + s2) * sqrtf(s2 + 1e-8f));
            vx *= fsc; vy *= fsc;
            if (pass < 2) {
                float* qd = &qsum[Kq * QSTR + pr * 2];
                qd[0] += vx; qd[1] += vy;
            } else {
                float* od = out + (size_t)(b0 + b) * 2048 + Kq * 64 + pr * 2;
                od[0] = vx; od[1] = vy;
            }
        }
        if (pass < 2) __syncthreads();   // qsum visible + qpart reads done
    }
}

extern "C" void kernel_launch(void* const* d_in, const int* in_sizes, int n_in,
                              void* d_out, int out_size, void* d_ws, size_t ws_size,
                              hipStream_t stream) {
    const float* x = (const float*)d_in[0];
    const float* W = (const float*)d_in[1];
    float* out = (float*)d_out;
    float* p   = (float*)d_ws;    // p owns the whole workspace

    // full batch in one shot if ws >= 128 MiB (proven); else 2 chunks
    const int chunk = (ws_size >= (size_t)134217728) ? 256 : 128;

    for (int b0 = 0; b0 < BATCH; b0 += chunk) {
        gemm_kernel<<<dim3(NEXT, PRE, chunk / 128), 256, 0, stream>>>(x, W, p, b0);
        route_kernel<<<chunk, 1024, 0, stream>>>(p, out, b0);
    }
}